// Round 5
// baseline (294.716 us; speedup 1.0000x reference)
//
#include <hip/hip_runtime.h>
#include <hip/hip_bf16.h>

#define NN 512
#define DD 128

typedef __bf16 bf16x8 __attribute__((ext_vector_type(8)));
typedef __bf16 bf16x4 __attribute__((ext_vector_type(4)));
typedef float f32x4 __attribute__((ext_vector_type(4)));
typedef float f32x2 __attribute__((ext_vector_type(2)));

static __device__ __forceinline__ f32x4 mfma16(bf16x8 a, bf16x8 b, f32x4 c) {
  return __builtin_amdgcn_mfma_f32_16x16x32_bf16(a, b, c, 0, 0, 0);
}

// ---------------- phase 0a: weight transposes to bf16 ----------------
__global__ void k_prep(const float* __restrict__ msg_w1,
                       const float* __restrict__ msg_w2,
                       __bf16* __restrict__ w1t, __bf16* __restrict__ w2t) {
  int t = blockIdx.x * 256 + threadIdx.x;   // 16384 total
  int e = t >> 7, k = t & 127;
  w1t[e * 128 + k] = (__bf16)msg_w1[(128 + k) * 128 + e];
  w2t[e * 128 + k] = (__bf16)msg_w2[k * 128 + e];
}

// ---------------- phase 0b: hjp[j][e] = h[j]@w1_h + b1 ----------------
__global__ void k_hjp(const float* __restrict__ h, const float* __restrict__ w1,
                      const float* __restrict__ b1, float* __restrict__ hjp) {
  __shared__ float hr[128];
  int j = blockIdx.x, t = threadIdx.x;
  hr[t] = h[j * 128 + t];
  __syncthreads();
  float acc = b1[t];
  #pragma unroll 8
  for (int k = 0; k < 128; k++) acc += hr[k] * w1[k * 128 + t];
  hjp[j * 128 + t] = acc;
}

// ---------------- phase 0c: cnt[i] = sum_j edge_mask[j][i] ----------------
__global__ void k_cnt(const int* __restrict__ emask, float* __restrict__ cnt) {
  int col = blockIdx.x * 128 + threadIdx.x;
  int s = 0;
  #pragma unroll 8
  for (int j = 0; j < NN; j++) s += emask[j * NN + col] ? 1 : 0;
  cnt[col] = (float)s;
}

// ---------------- phase 1: fused msgs + mask + agg-partial ----------------
// LDS: [0,34816) w1t[128][136] bf16 | [34816,69632) w2t[128][136] bf16.
// NO per-wave S buffer: GEMM1->GEMM2 operand transpose is a 4-lane shuffle.
// w1t region is reused as the f32 reduction buffer after a barrier.
#define LDS_BYTES 69632

// R1-R4 were all scratch-spill-bound (WRITE_SIZE 110-270MB vs 4MB
// programmed). Fix: peak live set ~100 VGPR (agg 32 + bfr 16 + p0/p1 8 +
// shuffle temps + addressing), all statically indexed, budget pinned at
// 128 via __launch_bounds__(512,4) -> 4 waves/SIMD, 2 blocks/CU (68KB LDS).
__global__ __launch_bounds__(512, 4) void k_main(
    const float* __restrict__ rel, const int* __restrict__ emask,
    const float* __restrict__ hjp, const __bf16* __restrict__ w1t_g,
    const __bf16* __restrict__ w2t_g, float* __restrict__ partial) {
  extern __shared__ char smem[];
  __bf16* w1t = (__bf16*)smem;
  __bf16* w2t = w1t + 128 * 136;
  const int tid = threadIdx.x;
  const int wave = tid >> 6;
  const int lane = tid & 63;
  const int l15 = lane & 15;
  const int q = lane >> 4;

  // stage weights into padded LDS (row stride 272B)
  #pragma unroll
  for (int t0 = 0; t0 < 4; t0++) {
    int t = tid + t0 * 512;
    int e = t >> 4, k8 = (t & 15) << 3;
    *(bf16x8*)(w1t + e * 136 + k8) = *(const bf16x8*)(w1t_g + e * 128 + k8);
    *(bf16x8*)(w2t + e * 136 + k8) = *(const bf16x8*)(w2t_g + e * 128 + k8);
  }
  __syncthreads();

  const int it = blockIdx.x >> 4;    // 0..31 : 16-row i-tile
  const int jc = blockIdx.x & 15;    // 0..15 : 32-col j-chunk
  const int irow = it * 16;

  // agg[cf][r] = sum_j M[i = irow + q*4 + r][d = cf*16 + l15]
  f32x4 agg[8];
  #pragma unroll
  for (int cf = 0; cf < 8; cf++) {
    f32x4 z = {0.f, 0.f, 0.f, 0.f};
    agg[cf] = z;
  }

  // shuffle source lanes (within the stride-16 lane group, same l15):
  // target lane (q,l15) pulls from lanes s0 = l15 + 32*(q&1), s1 = s0+16,
  // selecting the v0/v1 half by q>>1. (mapping verified per-lane)
  const int s0 = l15 + ((q & 1) << 5);
  const int s1 = s0 + 16;
  const bool hiHalf = (q >> 1) != 0;

  const int jbase = jc * 32 + wave * 4;
  #pragma unroll 1
  for (int jj = 0; jj < 4; jj++) {
    const int j = jbase + jj;

    // load 16 rel rows (GEMM1 B-operand): rel[j][irow+l15][kc*32+q*8 ..]
    bf16x8 bfr[4];
    const float* rowp = rel + ((size_t)j * NN + irow + l15) * DD + q * 8;
    #pragma unroll
    for (int kc = 0; kc < 4; kc++) {
      f32x4 x0 = *(const f32x4*)(rowp + kc * 32);
      f32x4 x1 = *(const f32x4*)(rowp + kc * 32 + 4);
      bf16x8 bb;
      bb[0] = (__bf16)x0[0]; bb[1] = (__bf16)x0[1];
      bb[2] = (__bf16)x0[2]; bb[3] = (__bf16)x0[3];
      bb[4] = (__bf16)x1[0]; bb[5] = (__bf16)x1[1];
      bb[6] = (__bf16)x1[2]; bb[7] = (__bf16)x1[3];
      bfr[kc] = bb;
    }

    float ms = emask[(size_t)j * NN + irow + l15] ? 1.f : 0.f;
    const float* hj = hjp + (size_t)j * DD;

    // interleaved GEMM1-pair -> silu -> shuffle -> GEMM2 k-tile, per eg
    #pragma unroll
    for (int eg = 0; eg < 4; eg++) {
      // GEMM1: PRE^T rows e in [32eg,32eg+16) and [32eg+16,32eg+32)
      f32x4 p0 = {0.f, 0.f, 0.f, 0.f};
      f32x4 p1 = {0.f, 0.f, 0.f, 0.f};
      #pragma unroll
      for (int kc = 0; kc < 4; kc++) {
        bf16x8 aw0 = *(const bf16x8*)(w1t + (eg * 32 + l15) * 136 + kc * 32 + q * 8);
        bf16x8 aw1 = *(const bf16x8*)(w1t + (eg * 32 + 16 + l15) * 136 + kc * 32 + q * 8);
        p0 = mfma16(aw0, bfr[kc], p0);
        p1 = mfma16(aw1, bfr[kc], p1);
      }
      // silu(pre + hjp) * mask -> bf16x4 pair
      // lane holds S[i=l15][e = 32eg + q*4 + r] (v0), +16 (v1)
      f32x4 hv0 = *(const f32x4*)(hj + eg * 32 + q * 4);
      f32x4 hv1 = *(const f32x4*)(hj + eg * 32 + 16 + q * 4);
      bf16x4 v0, v1;
      #pragma unroll
      for (int r = 0; r < 4; r++) {
        float x0 = p0[r] + hv0[r];
        float x1 = p1[r] + hv1[r];
        v0[r] = (__bf16)(ms * x0 / (1.f + __expf(-x0)));
        v1[r] = (__bf16)(ms * x1 / (1.f + __expf(-x1)));
      }
      // 4-lane shuffle: build aS = S[i=l15][e = 32eg + 8q + 0..7]
      int2 w0 = __builtin_bit_cast(int2, v0);
      int2 w1 = __builtin_bit_cast(int2, v1);
      int c00 = __shfl(w0.x, s0); int c01 = __shfl(w0.y, s0);
      int c02 = __shfl(w0.x, s1); int c03 = __shfl(w0.y, s1);
      int c10 = __shfl(w1.x, s0); int c11 = __shfl(w1.y, s0);
      int c12 = __shfl(w1.x, s1); int c13 = __shfl(w1.y, s1);
      int4 av;
      av.x = hiHalf ? c10 : c00;
      av.y = hiHalf ? c11 : c01;
      av.z = hiHalf ? c12 : c02;
      av.w = hiHalf ? c13 : c03;
      bf16x8 aS = __builtin_bit_cast(bf16x8, av);
      // GEMM2 k-tile eg: agg[i,d] += S[i, 32eg..+32) @ w2[32eg..+32, d]
      #pragma unroll
      for (int cf = 0; cf < 8; cf++) {
        bf16x8 wb = *(const bf16x8*)(w2t + (cf * 16 + l15) * 136 + eg * 32 + q * 8);
        agg[cf] = mfma16(aS, wb, agg[cf]);
      }
    }
  }

  // cross-wave reduction: reuse w1t region as 8 x [8][132] f32 bufs.
  // agg[cf][r] = M[i = irow + q*4 + r][d = cf*16 + l15]; two 8-row rounds.
  float* fbase = (float*)smem;
  float* fb = fbase + wave * (8 * 132);
  #pragma unroll
  for (int t = 0; t < 2; t++) {
    __syncthreads();   // round 0: all GEMM1 w1t reads done; round 1: prev reads done
    if ((q >> 1) == t) {
      #pragma unroll
      for (int cf = 0; cf < 8; cf++)
        #pragma unroll
        for (int r = 0; r < 4; r++)
          fb[((q & 1) * 4 + r) * 132 + cf * 16 + l15] = agg[cf][r];
    }
    __syncthreads();
    int row8 = tid >> 6;         // 0..7
    int d2 = (tid & 63) << 1;    // 0..126 step 2
    float a0 = 0.f, a1 = 0.f;
    #pragma unroll
    for (int w = 0; w < 8; w++) {
      const float* p = fbase + w * (8 * 132) + row8 * 132 + d2;
      a0 += p[0];
      a1 += p[1];
    }
    f32x2 sv = {a0, a1};
    *(f32x2*)(partial + ((size_t)jc * NN + irow + t * 8 + row8) * DD + d2) = sv;
  }
}

// ---------------- phase 2: reduce partials + update MLP + LayerNorm ----------------
__global__ void k_update(const float* __restrict__ h, const float* __restrict__ partial,
                         const float* __restrict__ b2, const float* __restrict__ cnt,
                         const float* __restrict__ uw1, const float* __restrict__ ub1,
                         const float* __restrict__ uw2, const float* __restrict__ ub2,
                         const float* __restrict__ g, const float* __restrict__ bb,
                         float* __restrict__ out) {
  __shared__ float uin[256];
  __shared__ float zl[128];
  __shared__ float ss[4];
  int i = blockIdx.x, t = threadIdx.x;
  float hv = h[i * 128 + t];
  float a = cnt[i] * b2[t];
  #pragma unroll
  for (int c = 0; c < 16; c++) a += partial[((size_t)c * NN + i) * DD + t];
  uin[t] = hv;
  uin[128 + t] = a;
  __syncthreads();
  float z = ub1[t];
  #pragma unroll 8
  for (int k = 0; k < 256; k++) z += uin[k] * uw1[k * 128 + t];
  z = z / (1.f + __expf(-z));
  zl[t] = z;
  __syncthreads();
  float dl = ub2[t];
  #pragma unroll 8
  for (int k = 0; k < 128; k++) dl += zl[k] * uw2[k * 128 + t];
  float x = hv + dl;
  float s1 = x, s2 = x * x;
  #pragma unroll
  for (int off = 32; off > 0; off >>= 1) {
    s1 += __shfl_down(s1, off, 64);
    s2 += __shfl_down(s2, off, 64);
  }
  if ((t & 63) == 0) { ss[(t >> 6) * 2] = s1; ss[(t >> 6) * 2 + 1] = s2; }
  __syncthreads();
  s1 = ss[0] + ss[2];
  s2 = ss[1] + ss[3];
  float mu = s1 * (1.f / 128.f);
  float var = s2 * (1.f / 128.f) - mu * mu;
  out[i * 128 + t] = (x - mu) * rsqrtf(var + 1e-5f) * g[t] + bb[t];
}

extern "C" void kernel_launch(void* const* d_in, const int* in_sizes, int n_in,
                              void* d_out, int out_size, void* d_ws, size_t ws_size,
                              hipStream_t stream) {
  const float* h      = (const float*)d_in[0];
  const float* rel    = (const float*)d_in[1];
  const int*   emask  = (const int*)d_in[2];
  const float* msg_w1 = (const float*)d_in[3];
  const float* msg_b1 = (const float*)d_in[4];
  const float* msg_w2 = (const float*)d_in[5];
  const float* msg_b2 = (const float*)d_in[6];
  const float* upd_w1 = (const float*)d_in[7];
  const float* upd_b1 = (const float*)d_in[8];
  const float* upd_w2 = (const float*)d_in[9];
  const float* upd_b2 = (const float*)d_in[10];
  const float* ln_g   = (const float*)d_in[11];
  const float* ln_b   = (const float*)d_in[12];
  float* out = (float*)d_out;

  char* ws = (char*)d_ws;
  float*  hjp     = (float*)ws;                        // 262144 B
  __bf16* w1t     = (__bf16*)(ws + 262144);            // 32768 B
  __bf16* w2t     = (__bf16*)(ws + 262144 + 32768);    // 32768 B
  float*  cnt     = (float*)(ws + 262144 + 65536);     // 2048 B
  float*  partial = (float*)(ws + 262144 + 65536 + 4096); // 4 MiB

  k_prep<<<64, 256, 0, stream>>>(msg_w1, msg_w2, w1t, w2t);
  k_hjp<<<512, 128, 0, stream>>>(h, msg_w1, msg_b1, hjp);
  k_cnt<<<4, 128, 0, stream>>>(emask, cnt);
  hipFuncSetAttribute((const void*)k_main,
                      hipFuncAttributeMaxDynamicSharedMemorySize, LDS_BYTES);
  k_main<<<512, 512, LDS_BYTES, stream>>>(rel, emask, hjp, w1t, w2t, partial);
  k_update<<<512, 128, 0, stream>>>(h, partial, msg_b2, cnt, upd_w1, upd_b1,
                                    upd_w2, upd_b2, ln_g, ln_b, out);
}

// Round 6
// 96.079 us; speedup vs baseline: 3.0674x; 3.0674x over previous
//
#include <hip/hip_runtime.h>
#include <hip/hip_bf16.h>

#define NN 512
#define DD 128

typedef __bf16 bf16x8 __attribute__((ext_vector_type(8)));
typedef float f32x4 __attribute__((ext_vector_type(4)));
typedef float f32x2 __attribute__((ext_vector_type(2)));

static __device__ __forceinline__ f32x4 mfma16(bf16x8 a, bf16x8 b, f32x4 c) {
  return __builtin_amdgcn_mfma_f32_16x16x32_bf16(a, b, c, 0, 0, 0);
}

// ---------------- phase 0a: w1_e transpose to bf16 ----------------
// w1t[e][k] = msg_w1[128+k][e]
__global__ void k_prep(const float* __restrict__ msg_w1,
                       __bf16* __restrict__ w1t) {
  int t = blockIdx.x * 256 + threadIdx.x;   // 16384 total
  int e = t >> 7, k = t & 127;
  w1t[e * 128 + k] = (__bf16)msg_w1[(128 + k) * 128 + e];
}

// ---------------- phase 0b: hjp[j][e] = h[j]@w1_h + b1 ----------------
__global__ void k_hjp(const float* __restrict__ h, const float* __restrict__ w1,
                      const float* __restrict__ b1, float* __restrict__ hjp) {
  __shared__ float hr[128];
  int j = blockIdx.x, t = threadIdx.x;
  hr[t] = h[j * 128 + t];
  __syncthreads();
  float acc = b1[t];
  #pragma unroll 8
  for (int k = 0; k < 128; k++) acc += hr[k] * w1[k * 128 + t];
  hjp[j * 128 + t] = acc;
}

// ---------------- phase 0c: cnt[i] = sum_j edge_mask[j][i] ----------------
__global__ void k_cnt(const int* __restrict__ emask, float* __restrict__ cnt) {
  int col = blockIdx.x * 128 + threadIdx.x;
  int s = 0;
  #pragma unroll 8
  for (int j = 0; j < NN; j++) s += emask[j * NN + col] ? 1 : 0;
  cnt[col] = (float)s;
}

// ---------------- phase 1: T[i][e] = sum_j mask[j,i]*silu(pre[j,i,e]) ----
// GEMM2 is hoisted OUT of the N^2 loop (linearity): hot loop = GEMM1 + silu
// + masked f32 accumulate. Live set ~85 VGPR (Tacc 32 + bfr 16 + p0/p1 8 +
// addr/transients) -- fits the allocator's empirical 96-128 budget with no
// spill (R1-R5 all died on scratch traffic, WRITE_SIZE 110-270MB).
// LDS: w1t[128][136] bf16 (34816 B), reused as 8 x [8][132] f32 reduce bufs.
#define LDS_BYTES 34816

__global__ __launch_bounds__(512, 1) void k_main(
    const float* __restrict__ rel, const int* __restrict__ emask,
    const float* __restrict__ hjp, const __bf16* __restrict__ w1t_g,
    float* __restrict__ partial) {
  extern __shared__ char smem[];
  __bf16* w1t = (__bf16*)smem;
  const int tid = threadIdx.x;
  const int wave = tid >> 6;
  const int lane = tid & 63;
  const int l15 = lane & 15;
  const int q = lane >> 4;

  // stage w1t into padded LDS (row stride 272B)
  {
    int t = tid * 8;                 // 512 threads x 8 bf16 = 4096 of 16384
    #pragma unroll
    for (int t0 = 0; t0 < 4; t0++) {
      int tt = t + t0 * 4096;
      int e = tt >> 7, k8 = tt & 127;
      *(bf16x8*)(w1t + e * 136 + k8) = *(const bf16x8*)(w1t_g + e * 128 + k8);
    }
  }
  __syncthreads();

  const int it = blockIdx.x >> 4;    // 0..31 : 16-row i-tile
  const int jc = blockIdx.x & 15;    // 0..15 : 32-col j-chunk
  const int irow = it * 16;

  // Tacc[ef][r] = T[i = l15][e = ef*16 + q*4 + r]  (f32, this wave's 4 j's)
  f32x4 Tacc[8];
  #pragma unroll
  for (int ef = 0; ef < 8; ef++) {
    f32x4 z = {0.f, 0.f, 0.f, 0.f};
    Tacc[ef] = z;
  }

  const int jbase = jc * 32 + wave * 4;
  #pragma unroll 1
  for (int jj = 0; jj < 4; jj++) {
    const int j = jbase + jj;

    // load 16 rel rows (GEMM1 B-operand): rel[j][irow+l15][kc*32+q*8 ..]
    bf16x8 bfr[4];
    const float* rowp = rel + ((size_t)j * NN + irow + l15) * DD + q * 8;
    #pragma unroll
    for (int kc = 0; kc < 4; kc++) {
      f32x4 x0 = *(const f32x4*)(rowp + kc * 32);
      f32x4 x1 = *(const f32x4*)(rowp + kc * 32 + 4);
      bf16x8 bb;
      bb[0] = (__bf16)x0[0]; bb[1] = (__bf16)x0[1];
      bb[2] = (__bf16)x0[2]; bb[3] = (__bf16)x0[3];
      bb[4] = (__bf16)x1[0]; bb[5] = (__bf16)x1[1];
      bb[6] = (__bf16)x1[2]; bb[7] = (__bf16)x1[3];
      bfr[kc] = bb;
    }

    float ms = emask[(size_t)j * NN + irow + l15] ? 1.f : 0.f;
    const float* hj = hjp + (size_t)j * DD;

    // per eg: GEMM1 rows [32eg,32eg+32) -> silu -> masked accumulate
    #pragma unroll
    for (int eg = 0; eg < 4; eg++) {
      f32x4 p0 = {0.f, 0.f, 0.f, 0.f};
      f32x4 p1 = {0.f, 0.f, 0.f, 0.f};
      #pragma unroll
      for (int kc = 0; kc < 4; kc++) {
        bf16x8 aw0 = *(const bf16x8*)(w1t + (eg * 32 + l15) * 136 + kc * 32 + q * 8);
        bf16x8 aw1 = *(const bf16x8*)(w1t + (eg * 32 + 16 + l15) * 136 + kc * 32 + q * 8);
        p0 = mfma16(aw0, bfr[kc], p0);
        p1 = mfma16(aw1, bfr[kc], p1);
      }
      // lane holds pre[e = 32eg + q*4 + r][i = l15] (p0), e+16 (p1)
      f32x4 hv0 = *(const f32x4*)(hj + eg * 32 + q * 4);
      f32x4 hv1 = *(const f32x4*)(hj + eg * 32 + 16 + q * 4);
      #pragma unroll
      for (int r = 0; r < 4; r++) {
        float x0 = p0[r] + hv0[r];
        float x1 = p1[r] + hv1[r];
        Tacc[2 * eg][r]     += ms * x0 / (1.f + __expf(-x0));
        Tacc[2 * eg + 1][r] += ms * x1 / (1.f + __expf(-x1));
      }
    }
  }

  // cross-wave reduction: reuse w1t region as 8 x [8][132] f32 bufs.
  // Tacc[ef][r] = T[i=l15][e=ef*16+q*4+r]; two 8-row rounds over i.
  float* fbase = (float*)smem;
  float* fb = fbase + wave * (8 * 132);
  #pragma unroll
  for (int t = 0; t < 2; t++) {
    __syncthreads();   // round 0: all w1t reads done; round 1: prev reads done
    if ((l15 >> 3) == t) {
      #pragma unroll
      for (int ef = 0; ef < 8; ef++)
        *(f32x4*)(fb + (l15 & 7) * 132 + ef * 16 + q * 4) = Tacc[ef];
    }
    __syncthreads();
    int row8 = tid >> 6;         // 0..7
    int e2 = (tid & 63) << 1;    // 0..126 step 2
    float a0 = 0.f, a1 = 0.f;
    #pragma unroll
    for (int w = 0; w < 8; w++) {
      const float* p = fbase + w * (8 * 132) + row8 * 132 + e2;
      a0 += p[0];
      a1 += p[1];
    }
    f32x2 sv = {a0, a1};
    *(f32x2*)(partial + ((size_t)jc * NN + irow + t * 8 + row8) * DD + e2) = sv;
  }
}

// ------- phase 2: T-reduce + GEMM2(f32) + update MLP + LayerNorm -------
__global__ void k_update(const float* __restrict__ h, const float* __restrict__ partial,
                         const float* __restrict__ w2, const float* __restrict__ b2,
                         const float* __restrict__ cnt,
                         const float* __restrict__ uw1, const float* __restrict__ ub1,
                         const float* __restrict__ uw2, const float* __restrict__ ub2,
                         const float* __restrict__ g, const float* __restrict__ bb,
                         float* __restrict__ out) {
  __shared__ float Trow[128];
  __shared__ float uin[256];
  __shared__ float zl[128];
  __shared__ float ss[4];
  int i = blockIdx.x, t = threadIdx.x;
  float hv = h[i * 128 + t];
  float ts = 0.f;
  #pragma unroll
  for (int c = 0; c < 16; c++) ts += partial[((size_t)c * NN + i) * DD + t];
  Trow[t] = ts;
  __syncthreads();
  // agg[d] = T[i,:] @ w2[:,d] + cnt[i]*b2[d]   (f32 GEMM2, hoisted)
  float a = cnt[i] * b2[t];
  #pragma unroll 8
  for (int e = 0; e < 128; e++) a += Trow[e] * w2[e * 128 + t];
  uin[t] = hv;
  uin[128 + t] = a;
  __syncthreads();
  float z = ub1[t];
  #pragma unroll 8
  for (int k = 0; k < 256; k++) z += uin[k] * uw1[k * 128 + t];
  z = z / (1.f + __expf(-z));
  zl[t] = z;
  __syncthreads();
  float dl = ub2[t];
  #pragma unroll 8
  for (int k = 0; k < 128; k++) dl += zl[k] * uw2[k * 128 + t];
  float x = hv + dl;
  float s1 = x, s2 = x * x;
  #pragma unroll
  for (int off = 32; off > 0; off >>= 1) {
    s1 += __shfl_down(s1, off, 64);
    s2 += __shfl_down(s2, off, 64);
  }
  if ((t & 63) == 0) { ss[(t >> 6) * 2] = s1; ss[(t >> 6) * 2 + 1] = s2; }
  __syncthreads();
  s1 = ss[0] + ss[2];
  s2 = ss[1] + ss[3];
  float mu = s1 * (1.f / 128.f);
  float var = s2 * (1.f / 128.f) - mu * mu;
  out[i * 128 + t] = (x - mu) * rsqrtf(var + 1e-5f) * g[t] + bb[t];
}

extern "C" void kernel_launch(void* const* d_in, const int* in_sizes, int n_in,
                              void* d_out, int out_size, void* d_ws, size_t ws_size,
                              hipStream_t stream) {
  const float* h      = (const float*)d_in[0];
  const float* rel    = (const float*)d_in[1];
  const int*   emask  = (const int*)d_in[2];
  const float* msg_w1 = (const float*)d_in[3];
  const float* msg_b1 = (const float*)d_in[4];
  const float* msg_w2 = (const float*)d_in[5];
  const float* msg_b2 = (const float*)d_in[6];
  const float* upd_w1 = (const float*)d_in[7];
  const float* upd_b1 = (const float*)d_in[8];
  const float* upd_w2 = (const float*)d_in[9];
  const float* upd_b2 = (const float*)d_in[10];
  const float* ln_g   = (const float*)d_in[11];
  const float* ln_b   = (const float*)d_in[12];
  float* out = (float*)d_out;

  char* ws = (char*)d_ws;
  float*  hjp     = (float*)ws;                        // 262144 B
  __bf16* w1t     = (__bf16*)(ws + 262144);            // 32768 B
  float*  cnt     = (float*)(ws + 262144 + 32768);     // 2048 B
  float*  partial = (float*)(ws + 262144 + 36864);     // 16*512*128*4 = 4 MiB

  k_prep<<<64, 256, 0, stream>>>(msg_w1, w1t);
  k_hjp<<<512, 128, 0, stream>>>(h, msg_w1, msg_b1, hjp);
  k_cnt<<<4, 128, 0, stream>>>(emask, cnt);
  hipFuncSetAttribute((const void*)k_main,
                      hipFuncAttributeMaxDynamicSharedMemorySize, LDS_BYTES);
  k_main<<<512, 512, LDS_BYTES, stream>>>(rel, emask, hjp, w1t, partial);
  k_update<<<512, 128, 0, stream>>>(h, partial, msg_w2, msg_b2, cnt,
                                    upd_w1, upd_b1, upd_w2, upd_b2,
                                    ln_g, ln_b, out);
}